// Round 1
// baseline (262.411 us; speedup 1.0000x reference)
//
#include <hip/hip_runtime.h>

typedef unsigned short UST;
typedef __attribute__((ext_vector_type(8))) short bf16x8;
typedef __attribute__((ext_vector_type(4))) float f32x4;

__device__ __forceinline__ UST f2bf(float f) {
  union { float f; unsigned int u; } x; x.f = f;
  unsigned int r = x.u + 0x7fffu + ((x.u >> 16) & 1u);
  return (UST)(r >> 16);
}

typedef const __attribute__((address_space(1))) unsigned int* gptr32;
typedef __attribute__((address_space(3))) unsigned int* lptr32;

// async global->LDS, 16B per lane; LDS dest = wave-uniform base + lane*16
__device__ __forceinline__ void load16(const void* g, void* l) {
  __builtin_amdgcn_global_load_lds((gptr32)(unsigned long long)g,
                                   (lptr32)(unsigned int)(unsigned long long)l,
                                   16, 0, 0);
}

// ---------------- fp32 -> bf16 weight conversion (4x 512x512) ----------------
__global__ __launch_bounds__(256) void conv_w(
    const float4* __restrict__ a, const float4* __restrict__ b,
    const float4* __restrict__ c, const float4* __restrict__ d,
    ushort4* __restrict__ oa, ushort4* __restrict__ ob,
    ushort4* __restrict__ oc, ushort4* __restrict__ od) {
  int i = blockIdx.x * 256 + threadIdx.x;  // 65536 float4s each
  float4 v;
  v = a[i]; oa[i] = make_ushort4(f2bf(v.x), f2bf(v.y), f2bf(v.z), f2bf(v.w));
  v = b[i]; ob[i] = make_ushort4(f2bf(v.x), f2bf(v.y), f2bf(v.z), f2bf(v.w));
  v = c[i]; oc[i] = make_ushort4(f2bf(v.x), f2bf(v.y), f2bf(v.z), f2bf(v.w));
  v = d[i]; od[i] = make_ushort4(f2bf(v.x), f2bf(v.y), f2bf(v.z), f2bf(v.w));
}

// ---------------- GroupNorm stats: one block per (b,g), 16ch x 1024 ----------
__global__ __launch_bounds__(256) void gn_stats(const float* __restrict__ inp,
                                                float* __restrict__ stats) {
  const int bg = blockIdx.x;  // b*32+g ; group block is contiguous 16384 floats
  const int tid = threadIdx.x;
  const float4* p = (const float4*)(inp + (size_t)bg * 16384);
  float s = 0.f, ss = 0.f;
#pragma unroll
  for (int i = 0; i < 16; i++) {
    float4 t = p[tid + i * 256];
    s += t.x + t.y + t.z + t.w;
    ss += t.x * t.x + t.y * t.y + t.z * t.z + t.w * t.w;
  }
  for (int o = 32; o >= 1; o >>= 1) { s += __shfl_xor(s, o); ss += __shfl_xor(ss, o); }
  __shared__ float red[8];
  const int w = tid >> 6;
  if ((tid & 63) == 0) { red[w * 2] = s; red[w * 2 + 1] = ss; }
  __syncthreads();
  if (tid == 0) {
    float S1 = red[0] + red[2] + red[4] + red[6];
    float S2 = red[1] + red[3] + red[5] + red[7];
    float mu = S1 * (1.f / 16384.f);
    float var = S2 * (1.f / 16384.f) - mu * mu;
    stats[bg * 2] = mu;
    stats[bg * 2 + 1] = rsqrtf(var + 1e-6f);
  }
}

// ------------- normalize + transpose: inp(b,c,n) -> Xnt(b,n,c) bf16 ----------
__global__ __launch_bounds__(64) void gn_apply(
    const float* __restrict__ inp, const float* __restrict__ gamma,
    const float* __restrict__ beta, const float* __restrict__ stats,
    UST* __restrict__ Xnt) {
  const int lane = threadIdx.x;
  const int nc = blockIdx.x, g = blockIdx.y, b = blockIdx.z;
  const float mu = stats[(b * 32 + g) * 2];
  const float rstd = stats[(b * 32 + g) * 2 + 1];
  const int n = nc * 64 + lane;
  UST o[16];
#pragma unroll
  for (int j = 0; j < 16; j++) {
    int c = g * 16 + j;
    float sc = gamma[c] * rstd;
    float sh = beta[c] - mu * sc;
    float x = inp[((size_t)b * 512 + c) * 1024 + n];  // coalesced over lanes
    o[j] = f2bf(x * sc + sh);
  }
  UST* dst = Xnt + ((size_t)b * 1024 + n) * 512 + g * 16;  // 32B per lane
#pragma unroll
  for (int q = 0; q < 4; q++)
    ((ushort4*)dst)[q] = make_ushort4(o[q * 4], o[q * 4 + 1], o[q * 4 + 2], o[q * 4 + 3]);
}

// ---------------- row softmax: S fp32 (16384x1024) -> P bf16 ----------------
__global__ __launch_bounds__(256) void softmax_k(const float* __restrict__ S,
                                                 UST* __restrict__ P) {
  const int w = threadIdx.x >> 6, lane = threadIdx.x & 63;
  const size_t row = (size_t)blockIdx.x * 4 + w;
  const float4* Sr = (const float4*)(S + row * 1024);
  float v[16];
#pragma unroll
  for (int j = 0; j < 4; j++) {
    float4 t = Sr[j * 64 + lane];
    v[j * 4 + 0] = t.x; v[j * 4 + 1] = t.y; v[j * 4 + 2] = t.z; v[j * 4 + 3] = t.w;
  }
  float m = v[0];
#pragma unroll
  for (int i = 1; i < 16; i++) m = fmaxf(m, v[i]);
#pragma unroll
  for (int o = 32; o >= 1; o >>= 1) m = fmaxf(m, __shfl_xor(m, o));
  float s = 0.f;
#pragma unroll
  for (int i = 0; i < 16; i++) { v[i] = __expf(v[i] - m); s += v[i]; }
#pragma unroll
  for (int o = 32; o >= 1; o >>= 1) s += __shfl_xor(s, o);
  const float rs = 1.f / s;
  ushort4* Pr = (ushort4*)(P + row * 1024);
#pragma unroll
  for (int j = 0; j < 4; j++)
    Pr[j * 64 + lane] = make_ushort4(f2bf(v[j * 4] * rs), f2bf(v[j * 4 + 1] * rs),
                                     f2bf(v[j * 4 + 2] * rs), f2bf(v[j * 4 + 3] * rs));
}

// ---------------- gemm_bt: C[i][j] = sum_k A[i][k]*B[j][k]  (+ epilogue) -----
// A: (M x K) K-major, B: (N x K) K-major, C: (M x N) row-major (ldc = N).
// EPI: 0 bf16 +bias[col] | 1 bf16 +bias[row] | 2 f32 *scale | 3 bf16 | 4 f32 +bias[row]+extra
template <int EPI>
__global__ __launch_bounds__(256, 2) void gemm_bt(
    const UST* __restrict__ A, const UST* __restrict__ B, void* __restrict__ C,
    const float* __restrict__ bias, const float* __restrict__ extra, float scale,
    int M, int N, int K, long strideA, long strideB, long strideC) {
  __shared__ __align__(16) UST lA[128 * 32];
  __shared__ __align__(16) UST lB[128 * 32];

  const int tid = threadIdx.x;
  const int z = blockIdx.z;
  const int m0 = blockIdx.y * 128;
  const int n0 = blockIdx.x * 128;
  const UST* Ab = A + (long)z * strideA;
  const UST* Bb = B + (long)z * strideB;

  const int w = tid >> 6, lane = tid & 63;
  const int quad = lane >> 4, l16 = lane & 15;
  const int wm = w >> 1, wn = w & 1;  // 2x2 waves, each 64x64

  f32x4 acc[4][4];
#pragma unroll
  for (int i = 0; i < 4; i++)
#pragma unroll
    for (int j = 0; j < 4; j++) acc[i][j] = f32x4{0.f, 0.f, 0.f, 0.f};

  // staging: 512 16B-chunks per tile; chunk = row*4 + kc ; lane order matches LDS
  const int rowa = tid >> 2;      // 0..63
  const int kc = (tid & 3) * 8;   // k element offset of 8-elem chunk
  const UST* gA = Ab + (size_t)(m0 + rowa) * K + kc;
  const UST* gB = Bb + (size_t)(n0 + rowa) * K + kc;
  char* lAw = (char*)lA + (w << 10);
  char* lBw = (char*)lB + (w << 10);

  for (int k0 = 0; k0 < K; k0 += 32) {
    __syncthreads();  // previous iter's LDS reads done
    load16(gA, lAw);
    load16(gA + (size_t)64 * K, lAw + 4096);
    load16(gB, lBw);
    load16(gB + (size_t)64 * K, lBw + 4096);
    gA += 32; gB += 32;
    __syncthreads();  // staging visible (vmcnt drained by barrier)
    bf16x8 af[4], bfr[4];
#pragma unroll
    for (int i = 0; i < 4; i++)
      af[i] = *(const bf16x8*)(lA + (wm * 64 + i * 16 + l16) * 32 + quad * 8);
#pragma unroll
    for (int j = 0; j < 4; j++)
      bfr[j] = *(const bf16x8*)(lB + (wn * 64 + j * 16 + l16) * 32 + quad * 8);
#pragma unroll
    for (int i = 0; i < 4; i++)
#pragma unroll
      for (int j = 0; j < 4; j++)
        acc[i][j] = __builtin_amdgcn_mfma_f32_16x16x32_bf16(af[i], bfr[j], acc[i][j], 0, 0, 0);
  }

  // C/D layout (verified m89/m91): col = lane&15, row = quad*4 + reg
  const int gr0 = m0 + wm * 64 + quad * 4;
  const int gc0 = n0 + wn * 64 + l16;
  if constexpr (EPI == 2 || EPI == 4) {
    float* Cb = (float*)C + (long)z * strideC;
#pragma unroll
    for (int i = 0; i < 4; i++)
#pragma unroll
      for (int j = 0; j < 4; j++) {
        const int gc = gc0 + j * 16;
#pragma unroll
        for (int r = 0; r < 4; r++) {
          const int gr = gr0 + i * 16 + r;
          float v = acc[i][j][r];
          if constexpr (EPI == 2) v *= scale;
          if constexpr (EPI == 4) v += bias[gr] + extra[(long)z * strideC + (size_t)gr * N + gc];
          Cb[(size_t)gr * N + gc] = v;
        }
      }
  } else {
    UST* Cb = (UST*)C + (long)z * strideC;
#pragma unroll
    for (int i = 0; i < 4; i++)
#pragma unroll
      for (int j = 0; j < 4; j++) {
        const int gc = gc0 + j * 16;
        float bc = 0.f;
        if constexpr (EPI == 0) bc = bias[gc];
#pragma unroll
        for (int r = 0; r < 4; r++) {
          const int gr = gr0 + i * 16 + r;
          float v = acc[i][j][r] + bc;
          if constexpr (EPI == 1) v += bias[gr];
          Cb[(size_t)gr * N + gc] = f2bf(v);
        }
      }
  }
}

extern "C" void kernel_launch(void* const* d_in, const int* in_sizes, int n_in,
                              void* d_out, int out_size, void* d_ws, size_t ws_size,
                              hipStream_t stream) {
  const float* inp   = (const float*)d_in[0];
  const float* gamma = (const float*)d_in[1];
  const float* beta  = (const float*)d_in[2];
  const float* Wq    = (const float*)d_in[3];
  const float* bq    = (const float*)d_in[4];
  const float* Wk    = (const float*)d_in[5];
  const float* bk    = (const float*)d_in[6];
  const float* Wv    = (const float*)d_in[7];
  const float* bv    = (const float*)d_in[8];
  const float* Wo    = (const float*)d_in[9];
  const float* bo    = (const float*)d_in[10];
  float* out = (float*)d_out;
  char* ws = (char*)d_ws;

  // workspace layout (bytes)
  UST*   Xnt   = (UST*)(ws);                          // 16 MB (B,N,C) bf16; reused as At
  UST*   Qt    = (UST*)(ws + ((size_t)16 << 20));     // 16 MB; reused as P (lower half)
  UST*   Kt    = (UST*)(ws + ((size_t)32 << 20));     // 16 MB; reused as P (upper half)
  UST*   V     = (UST*)(ws + ((size_t)48 << 20));     // 16 MB (B,C,M) bf16
  float* S     = (float*)(ws + ((size_t)64 << 20));   // 64 MB (B,N,M) fp32
  float* stats = (float*)(ws + ((size_t)128 << 20));  // 8 KB
  UST*   Wqb   = (UST*)(ws + ((size_t)128 << 20) + 8192);
  UST*   Wkb   = Wqb + 262144;
  UST*   Wvb   = Wkb + 262144;
  UST*   Wob   = Wvb + 262144;
  UST*   P     = Qt;   // 32 MB bf16, overwrites dead Qt+Kt
  UST*   At    = Xnt;  // 16 MB bf16, overwrites dead Xnt

  conv_w<<<256, 256, 0, stream>>>((const float4*)Wq, (const float4*)Wk,
                                  (const float4*)Wv, (const float4*)Wo,
                                  (ushort4*)Wqb, (ushort4*)Wkb, (ushort4*)Wvb, (ushort4*)Wob);
  gn_stats<<<512, 256, 0, stream>>>(inp, stats);
  gn_apply<<<dim3(16, 32, 16), 64, 0, stream>>>(inp, gamma, beta, stats, Xnt);

  // Qt(B*N,512) = Xnt @ Wq^T + bq[col]
  gemm_bt<0><<<dim3(4, 128, 1), 256, 0, stream>>>(Xnt, Wqb, Qt, bq, nullptr, 1.f,
                                                  16384, 512, 512, 0, 0, 0);
  gemm_bt<0><<<dim3(4, 128, 1), 256, 0, stream>>>(Xnt, Wkb, Kt, bk, nullptr, 1.f,
                                                  16384, 512, 512, 0, 0, 0);
  // V(b: 512x1024) = Wv @ Xnt_b^T + bv[row]
  gemm_bt<1><<<dim3(8, 4, 16), 256, 0, stream>>>(Wvb, Xnt, V, bv, nullptr, 1.f,
                                                 512, 1024, 512, 0, 524288, 524288);
  // S(b: 1024x1024) = (Qt_b @ Kt_b^T) / sqrt(512)
  gemm_bt<2><<<dim3(8, 8, 16), 256, 0, stream>>>(Qt, Kt, S, nullptr, nullptr,
                                                 0.04419417382415922f,
                                                 1024, 1024, 512, 524288, 524288, 1048576);
  softmax_k<<<4096, 256, 0, stream>>>(S, P);
  // At(b: 1024x512) = P_b @ V_b^T
  gemm_bt<3><<<dim3(4, 8, 16), 256, 0, stream>>>(P, V, At, nullptr, nullptr, 1.f,
                                                 1024, 512, 1024, 1048576, 524288, 524288);
  // out(b: 512x1024) = Wo @ At_b^T + bo[row] + inp
  gemm_bt<4><<<dim3(8, 4, 16), 256, 0, stream>>>(Wob, At, out, bo, inp, 1.f,
                                                 512, 1024, 512, 0, 524288, 524288);
}

// Round 2
// 245.087 us; speedup vs baseline: 1.0707x; 1.0707x over previous
//
#include <hip/hip_runtime.h>

typedef unsigned short UST;
typedef __attribute__((ext_vector_type(8))) short bf16x8;
typedef __attribute__((ext_vector_type(8))) unsigned short us8;
typedef __attribute__((ext_vector_type(4))) float f32x4;

__device__ __forceinline__ UST f2bf(float f) {
  union { float f; unsigned int u; } x; x.f = f;
  unsigned int r = x.u + 0x7fffu + ((x.u >> 16) & 1u);
  return (UST)(r >> 16);
}
__device__ __forceinline__ float bf2f(UST h) {
  union { unsigned int u; float f; } x; x.u = ((unsigned int)h) << 16;
  return x.f;
}

typedef const __attribute__((address_space(1))) unsigned int* gptr32;
typedef __attribute__((address_space(3))) unsigned int* lptr32;

// async global->LDS, 16B per lane; LDS dest = wave-uniform base + lane*16
__device__ __forceinline__ void load16(const void* g, void* l) {
  __builtin_amdgcn_global_load_lds((gptr32)(unsigned long long)g,
                                   (lptr32)(unsigned int)(unsigned long long)l,
                                   16, 0, 0);
}

// ---- fp32 -> bf16 weight conversion; Wq+Wk packed into Wqk; bqk concat ----
__global__ __launch_bounds__(256) void conv_w(
    const float4* __restrict__ a, const float4* __restrict__ b,
    const float4* __restrict__ c, const float4* __restrict__ d,
    ushort4* __restrict__ oa, ushort4* __restrict__ ob,
    ushort4* __restrict__ oc, ushort4* __restrict__ od,
    const float4* __restrict__ bq4, const float4* __restrict__ bk4,
    float4* __restrict__ bqk4) {
  int i = blockIdx.x * 256 + threadIdx.x;  // 65536 float4s each matrix
  float4 v;
  v = a[i]; oa[i] = make_ushort4(f2bf(v.x), f2bf(v.y), f2bf(v.z), f2bf(v.w));
  v = b[i]; ob[i] = make_ushort4(f2bf(v.x), f2bf(v.y), f2bf(v.z), f2bf(v.w));
  v = c[i]; oc[i] = make_ushort4(f2bf(v.x), f2bf(v.y), f2bf(v.z), f2bf(v.w));
  v = d[i]; od[i] = make_ushort4(f2bf(v.x), f2bf(v.y), f2bf(v.z), f2bf(v.w));
  if (blockIdx.x == 0) {
    int t = threadIdx.x;  // 256 float4 = 1024 floats
    bqk4[t] = (t < 128) ? bq4[t] : bk4[t - 128];
  }
}

// ---- fused GroupNorm: stats + normalize + transposed-interleaved write -----
// Xnt layout per batch: element (n,c) at (c>>3)*8192 + n*8 + (c&7)  [bf16]
__global__ __launch_bounds__(256) void gn_fused(
    const float* __restrict__ inp, const float* __restrict__ gamma,
    const float* __restrict__ beta, UST* __restrict__ Xnt) {
  const int g = blockIdx.x & 31, b = blockIdx.x >> 5;
  const int tid = threadIdx.x;
  const float* base = inp + ((size_t)b * 32 + g) * 16384;  // 16ch x 1024, contiguous
  const float4* p4 = (const float4*)base;
  float s = 0.f, ss = 0.f;
#pragma unroll
  for (int i = 0; i < 16; i++) {
    float4 t = p4[tid + i * 256];
    s += t.x + t.y + t.z + t.w;
    ss += t.x * t.x + t.y * t.y + t.z * t.z + t.w * t.w;
  }
  for (int o = 32; o >= 1; o >>= 1) { s += __shfl_xor(s, o); ss += __shfl_xor(ss, o); }
  __shared__ float red[8];
  __shared__ float mu_s, rstd_s;
  const int w = tid >> 6;
  if ((tid & 63) == 0) { red[w * 2] = s; red[w * 2 + 1] = ss; }
  __syncthreads();
  if (tid == 0) {
    float S1 = red[0] + red[2] + red[4] + red[6];
    float S2 = red[1] + red[3] + red[5] + red[7];
    float mu = S1 * (1.f / 16384.f);
    float var = S2 * (1.f / 16384.f) - mu * mu;
    mu_s = mu; rstd_s = rsqrtf(var + 1e-6f);
  }
  __syncthreads();
  const float mu = mu_s, rstd = rstd_s;
  // pass 2: re-read (L2-hot), write interleaved-transposed, fully coalesced
#pragma unroll
  for (int cc = 0; cc < 2; cc++) {
    const int ccg = g * 2 + cc;  // 8-channel chunk index
    float sc[8], sh[8];
#pragma unroll
    for (int j = 0; j < 8; j++) {
      int ch = ccg * 8 + j;
      sc[j] = gamma[ch] * rstd;
      sh[j] = beta[ch] - mu * sc[j];
    }
#pragma unroll
    for (int i = 0; i < 4; i++) {
      const int n = tid + i * 256;
      us8 v;
#pragma unroll
      for (int j = 0; j < 8; j++) {
        float x = inp[((size_t)b * 512 + ccg * 8 + j) * 1024 + n];
        v[j] = f2bf(x * sc[j] + sh[j]);
      }
      *(us8*)(Xnt + (size_t)b * 524288 + (size_t)ccg * 8192 + (size_t)n * 8) = v;
    }
  }
}

// ---- row softmax on bf16 scores: S(16384x1024) bf16 -> P bf16 --------------
__global__ __launch_bounds__(256) void softmax_k(const UST* __restrict__ S,
                                                 UST* __restrict__ P) {
  const int w = threadIdx.x >> 6, lane = threadIdx.x & 63;
  const size_t row = (size_t)blockIdx.x * 4 + w;
  const us8* Sr = (const us8*)(S + row * 1024);  // 128 us8 per row
  us8 a = Sr[lane], b = Sr[64 + lane];
  float v[16];
#pragma unroll
  for (int j = 0; j < 8; j++) { v[j] = bf2f(a[j]); v[8 + j] = bf2f(b[j]); }
  float m = v[0];
#pragma unroll
  for (int i = 1; i < 16; i++) m = fmaxf(m, v[i]);
#pragma unroll
  for (int o = 32; o >= 1; o >>= 1) m = fmaxf(m, __shfl_xor(m, o));
  float s = 0.f;
#pragma unroll
  for (int i = 0; i < 16; i++) { v[i] = __expf(v[i] - m); s += v[i]; }
#pragma unroll
  for (int o = 32; o >= 1; o >>= 1) s += __shfl_xor(s, o);
  const float rs = 1.f / s;
  us8* Pr = (us8*)(P + row * 1024);
  us8 oa, ob;
#pragma unroll
  for (int j = 0; j < 8; j++) { oa[j] = f2bf(v[j] * rs); ob[j] = f2bf(v[8 + j] * rs); }
  Pr[lane] = oa; Pr[64 + lane] = ob;
}

// ---- gemm_bt: C[i][j] = sum_k A[i][k]*B[j][k]  (+ epilogue) ----------------
// Generalized addressing: 16B chunk (row, kchunk) of operand X lives at
//   row*rsX + kchunk_lane*csX, advancing ssX elements per 32-k step.
// Standard K-major: rs=ld, cs=8, ss=32. Interleaved [k/8][n][8]: rs=8, cs=8192, ss=32768.
// EPI: 0 bf16 +bias[col] | 1 bf16 +bias[row] | 3 bf16 | 4 f32 +bias[row]+extra | 5 bf16 *scale
template <int EPI>
__global__ __launch_bounds__(256, 2) void gemm_bt(
    const UST* __restrict__ A, const UST* __restrict__ B, void* __restrict__ C,
    const float* __restrict__ bias, const float* __restrict__ extra, float scale,
    int N, int K, int ldc,
    int rsA, int csA, int ssA, int rsB, int csB, int ssB,
    long zA, long zB, long zC) {
  __shared__ __align__(16) UST lA[128 * 32];
  __shared__ __align__(16) UST lB[128 * 32];

  const int tid = threadIdx.x;
  const int z = blockIdx.z;
  const int m0 = blockIdx.y * 128;
  const int n0 = blockIdx.x * 128;
  const UST* Ab = A + (long)z * zA;
  const UST* Bb = B + (long)z * zB;

  const int w = tid >> 6, lane = tid & 63;
  const int quad = lane >> 4, l16 = lane & 15;
  const int wm = w >> 1, wn = w & 1;  // 2x2 waves, each 64x64

  f32x4 acc[4][4];
#pragma unroll
  for (int i = 0; i < 4; i++)
#pragma unroll
    for (int j = 0; j < 4; j++) acc[i][j] = f32x4{0.f, 0.f, 0.f, 0.f};

  const int rowa = tid >> 2;     // 0..63
  const int kchunk = tid & 3;    // which 8-elem chunk of the 32-k step
  const UST* gA = Ab + (size_t)(m0 + rowa) * rsA + (size_t)kchunk * csA;
  const UST* gB = Bb + (size_t)(n0 + rowa) * rsB + (size_t)kchunk * csB;
  char* lAw = (char*)lA + (w << 10);
  char* lBw = (char*)lB + (w << 10);

  for (int k0 = 0; k0 < K; k0 += 32) {
    __syncthreads();
    load16(gA, lAw);
    load16(gA + (size_t)64 * rsA, lAw + 4096);
    load16(gB, lBw);
    load16(gB + (size_t)64 * rsB, lBw + 4096);
    gA += ssA; gB += ssB;
    __syncthreads();
    bf16x8 af[4], bfr[4];
#pragma unroll
    for (int i = 0; i < 4; i++)
      af[i] = *(const bf16x8*)(lA + (wm * 64 + i * 16 + l16) * 32 + quad * 8);
#pragma unroll
    for (int j = 0; j < 4; j++)
      bfr[j] = *(const bf16x8*)(lB + (wn * 64 + j * 16 + l16) * 32 + quad * 8);
#pragma unroll
    for (int i = 0; i < 4; i++)
#pragma unroll
      for (int j = 0; j < 4; j++)
        acc[i][j] = __builtin_amdgcn_mfma_f32_16x16x32_bf16(af[i], bfr[j], acc[i][j], 0, 0, 0);
  }

  // C/D layout (verified m89/m91): col = lane&15, row = quad*4 + reg
  const int gr0 = m0 + wm * 64 + quad * 4;
  const int gc0 = n0 + wn * 64 + l16;
  if constexpr (EPI == 4) {
    float* Cb = (float*)C + (long)z * zC;
#pragma unroll
    for (int i = 0; i < 4; i++)
#pragma unroll
      for (int j = 0; j < 4; j++) {
        const int gc = gc0 + j * 16;
#pragma unroll
        for (int r = 0; r < 4; r++) {
          const int gr = gr0 + i * 16 + r;
          float v = acc[i][j][r] + bias[gr] + extra[(long)z * zC + (size_t)gr * ldc + gc];
          Cb[(size_t)gr * ldc + gc] = v;
        }
      }
  } else {
    UST* Cb = (UST*)C + (long)z * zC;
#pragma unroll
    for (int i = 0; i < 4; i++)
#pragma unroll
      for (int j = 0; j < 4; j++) {
        const int gc = gc0 + j * 16;
        float bc = 0.f;
        if constexpr (EPI == 0) bc = bias[gc];
#pragma unroll
        for (int r = 0; r < 4; r++) {
          const int gr = gr0 + i * 16 + r;
          float v = acc[i][j][r] + bc;
          if constexpr (EPI == 1) v += bias[gr];
          if constexpr (EPI == 5) v *= scale;
          Cb[(size_t)gr * ldc + gc] = f2bf(v);
        }
      }
  }
}

extern "C" void kernel_launch(void* const* d_in, const int* in_sizes, int n_in,
                              void* d_out, int out_size, void* d_ws, size_t ws_size,
                              hipStream_t stream) {
  const float* inp   = (const float*)d_in[0];
  const float* gamma = (const float*)d_in[1];
  const float* beta  = (const float*)d_in[2];
  const float* Wq    = (const float*)d_in[3];
  const float* bq    = (const float*)d_in[4];
  const float* Wk    = (const float*)d_in[5];
  const float* bk    = (const float*)d_in[6];
  const float* Wv    = (const float*)d_in[7];
  const float* bv    = (const float*)d_in[8];
  const float* Wo    = (const float*)d_in[9];
  const float* bo    = (const float*)d_in[10];
  float* out = (float*)d_out;
  char* ws = (char*)d_ws;

  // workspace layout (bytes)
  UST*   Xnt  = (UST*)(ws);                          // 16 MB interleaved (b,c/8,n,8); reused as At
  UST*   QKt  = (UST*)(ws + ((size_t)16 << 20));     // 32 MB (b,n,1024): Q cols 0-511, K 512-1023; reused as P
  UST*   V    = (UST*)(ws + ((size_t)48 << 20));     // 16 MB (b,c,m) bf16
  UST*   S    = (UST*)(ws + ((size_t)64 << 20));     // 32 MB (b,n,m) bf16
  float* bqk  = (float*)(ws + ((size_t)96 << 20));   // 4 KB
  UST*   Wqkb = (UST*)(ws + ((size_t)96 << 20) + 8192);  // 1 MB (1024x512)
  UST*   Wvb  = Wqkb + 524288;                       // 512 KB
  UST*   Wob  = Wvb + 262144;                        // 512 KB
  UST*   P    = QKt;   // overwrites dead QKt
  UST*   At   = Xnt;   // overwrites dead Xnt

  conv_w<<<256, 256, 0, stream>>>(
      (const float4*)Wq, (const float4*)Wk, (const float4*)Wv, (const float4*)Wo,
      (ushort4*)Wqkb, (ushort4*)(Wqkb + 262144), (ushort4*)Wvb, (ushort4*)Wob,
      (const float4*)bq, (const float4*)bk, (float4*)bqk);
  gn_fused<<<512, 256, 0, stream>>>(inp, gamma, beta, Xnt);

  // QKt(b: 1024x1024) = Xnt_b @ Wqk^T + bqk[col]   (A interleaved)
  gemm_bt<0><<<dim3(8, 8, 16), 256, 0, stream>>>(
      Xnt, Wqkb, QKt, bqk, nullptr, 1.f,
      1024, 512, 1024, 8, 8192, 32768, 512, 8, 32, 524288, 0, 1048576);
  // V(b: 512x1024) = Wv @ Xnt_b^T + bv[row]        (B interleaved)
  gemm_bt<1><<<dim3(8, 4, 16), 256, 0, stream>>>(
      Wvb, Xnt, V, bv, nullptr, 1.f,
      1024, 512, 1024, 512, 8, 32, 8, 8192, 32768, 0, 524288, 524288);
  // S(b: 1024x1024) bf16 = (Q_b @ K_b^T) / sqrt(512)
  gemm_bt<5><<<dim3(8, 8, 16), 256, 0, stream>>>(
      QKt, QKt + 512, S, nullptr, nullptr, 0.04419417382415922f,
      1024, 512, 1024, 1024, 8, 32, 1024, 8, 32, 1048576, 1048576, 1048576);
  softmax_k<<<4096, 256, 0, stream>>>(S, P);
  // At(b: 1024x512) = P_b @ V_b^T
  gemm_bt<3><<<dim3(4, 8, 16), 256, 0, stream>>>(
      P, V, At, nullptr, nullptr, 1.f,
      512, 1024, 512, 1024, 8, 32, 1024, 8, 32, 1048576, 524288, 524288);
  // out(b: 512x1024) = Wo @ At_b^T + bo[row] + inp
  gemm_bt<4><<<dim3(8, 4, 16), 256, 0, stream>>>(
      Wob, At, out, bo, inp, 1.f,
      1024, 512, 1024, 512, 8, 32, 512, 8, 32, 0, 524288, 524288);
}

// Round 3
// 244.915 us; speedup vs baseline: 1.0714x; 1.0007x over previous
//
#include <hip/hip_runtime.h>

typedef unsigned short UST;
typedef __attribute__((ext_vector_type(8))) short bf16x8;
typedef __attribute__((ext_vector_type(8))) unsigned short us8;
typedef __attribute__((ext_vector_type(4))) float f32x4;

__device__ __forceinline__ UST f2bf(float f) {
  union { float f; unsigned int u; } x; x.f = f;
  unsigned int r = x.u + 0x7fffu + ((x.u >> 16) & 1u);
  return (UST)(r >> 16);
}
__device__ __forceinline__ float bf2f(UST h) {
  union { unsigned int u; float f; } x; x.u = ((unsigned int)h) << 16;
  return x.f;
}

typedef const __attribute__((address_space(1))) unsigned int* gptr32;
typedef __attribute__((address_space(3))) unsigned int* lptr32;

// async global->LDS, 16B per lane; LDS dest = wave-uniform base + lane*16
__device__ __forceinline__ void load16(const void* g, void* l) {
  __builtin_amdgcn_global_load_lds((gptr32)(unsigned long long)g,
                                   (lptr32)(unsigned int)(unsigned long long)l,
                                   16, 0, 0);
}

// ---- fp32 -> bf16 weights: Wq,Wk,Wv packed -> Wqkv (1536x512); Wo; bqkv ----
__global__ __launch_bounds__(256) void conv_w(
    const float4* __restrict__ wq, const float4* __restrict__ wk,
    const float4* __restrict__ wv, const float4* __restrict__ wo,
    ushort4* __restrict__ oqkv, ushort4* __restrict__ owo,
    const float4* __restrict__ bq4, const float4* __restrict__ bk4,
    const float4* __restrict__ bv4, float4* __restrict__ bqkv4) {
  int i = blockIdx.x * 256 + threadIdx.x;  // 65536 float4 per matrix
  float4 v;
  v = wq[i]; oqkv[i]          = make_ushort4(f2bf(v.x), f2bf(v.y), f2bf(v.z), f2bf(v.w));
  v = wk[i]; oqkv[i + 65536]  = make_ushort4(f2bf(v.x), f2bf(v.y), f2bf(v.z), f2bf(v.w));
  v = wv[i]; oqkv[i + 131072] = make_ushort4(f2bf(v.x), f2bf(v.y), f2bf(v.z), f2bf(v.w));
  v = wo[i]; owo[i]           = make_ushort4(f2bf(v.x), f2bf(v.y), f2bf(v.z), f2bf(v.w));
  if (blockIdx.x < 2) {
    int t = blockIdx.x * 256 + threadIdx.x;  // 384 float4 = 1536 floats
    if (t < 384) bqkv4[t] = (t < 128) ? bq4[t] : (t < 256 ? bk4[t - 128] : bv4[t - 256]);
  }
}

// ---- fused GroupNorm: stats + normalize + transposed-interleaved write -----
// Xnt layout per batch: element (n,c) at (c>>3)*8192 + n*8 + (c&7)  [bf16]
__global__ __launch_bounds__(256) void gn_fused(
    const float* __restrict__ inp, const float* __restrict__ gamma,
    const float* __restrict__ beta, UST* __restrict__ Xnt) {
  const int g = blockIdx.x & 31, b = blockIdx.x >> 5;
  const int tid = threadIdx.x;
  const float* base = inp + ((size_t)b * 32 + g) * 16384;  // 16ch x 1024 contiguous
  const float4* p4 = (const float4*)base;
  float s = 0.f, ss = 0.f;
#pragma unroll
  for (int i = 0; i < 16; i++) {
    float4 t = p4[tid + i * 256];
    s += t.x + t.y + t.z + t.w;
    ss += t.x * t.x + t.y * t.y + t.z * t.z + t.w * t.w;
  }
  for (int o = 32; o >= 1; o >>= 1) { s += __shfl_xor(s, o); ss += __shfl_xor(ss, o); }
  __shared__ float red[8];
  __shared__ float mu_s, rstd_s;
  const int w = tid >> 6;
  if ((tid & 63) == 0) { red[w * 2] = s; red[w * 2 + 1] = ss; }
  __syncthreads();
  if (tid == 0) {
    float S1 = red[0] + red[2] + red[4] + red[6];
    float S2 = red[1] + red[3] + red[5] + red[7];
    float mu = S1 * (1.f / 16384.f);
    float var = S2 * (1.f / 16384.f) - mu * mu;
    mu_s = mu; rstd_s = rsqrtf(var + 1e-6f);
  }
  __syncthreads();
  const float mu = mu_s, rstd = rstd_s;
#pragma unroll
  for (int cc = 0; cc < 2; cc++) {
    const int ccg = g * 2 + cc;  // 8-channel chunk index
    float sc[8], sh[8];
#pragma unroll
    for (int j = 0; j < 8; j++) {
      int ch = ccg * 8 + j;
      sc[j] = gamma[ch] * rstd;
      sh[j] = beta[ch] - mu * sc[j];
    }
#pragma unroll
    for (int i = 0; i < 4; i++) {
      const int n = tid + i * 256;
      us8 v;
#pragma unroll
      for (int j = 0; j < 8; j++) {
        float x = inp[((size_t)b * 512 + ccg * 8 + j) * 1024 + n];
        v[j] = f2bf(x * sc[j] + sh[j]);
      }
      *(us8*)(Xnt + (size_t)b * 524288 + (size_t)ccg * 8192 + (size_t)n * 8) = v;
    }
  }
}

// ---- row softmax on bf16 scores: S(16384x1024) bf16 -> P bf16 --------------
__global__ __launch_bounds__(256) void softmax_k(const UST* __restrict__ S,
                                                 UST* __restrict__ P) {
  const int w = threadIdx.x >> 6, lane = threadIdx.x & 63;
  const size_t row = (size_t)blockIdx.x * 4 + w;
  const us8* Sr = (const us8*)(S + row * 1024);
  us8 a = Sr[lane], b = Sr[64 + lane];
  float v[16];
#pragma unroll
  for (int j = 0; j < 8; j++) { v[j] = bf2f(a[j]); v[8 + j] = bf2f(b[j]); }
  float m = v[0];
#pragma unroll
  for (int i = 1; i < 16; i++) m = fmaxf(m, v[i]);
#pragma unroll
  for (int o = 32; o >= 1; o >>= 1) m = fmaxf(m, __shfl_xor(m, o));
  float s = 0.f;
#pragma unroll
  for (int i = 0; i < 16; i++) { v[i] = __expf(v[i] - m); s += v[i]; }
#pragma unroll
  for (int o = 32; o >= 1; o >>= 1) s += __shfl_xor(s, o);
  const float rs = 1.f / s;
  us8* Pr = (us8*)(P + row * 1024);
  us8 oa, ob;
#pragma unroll
  for (int j = 0; j < 8; j++) { oa[j] = f2bf(v[j] * rs); ob[j] = f2bf(v[8 + j] * rs); }
  Pr[lane] = oa; Pr[64 + lane] = ob;
}

// ---- gemm_bt: C[i][j] = sum_k A[i][k]*B[j][k], LDS-staged coalesced epilogue
// 16B chunk (row,kchunk) of operand at row*rs + kchunk*cs, advancing ss per 32-k.
// EPI 6: QKV  - bf16 +bias[col]; n0<1024 -> QKt row-major; n0>=1024 -> V transposed
//               (V base passed via `extra`, z-stride 524288)
// EPI 5: bf16 *scale | EPI 3: bf16 | EPI 4: f32 +bias[row] +extra (residual)
template <int EPI>
__global__ __launch_bounds__(256, 2) void gemm_bt(
    const UST* __restrict__ A, const UST* __restrict__ B, void* __restrict__ C,
    const float* __restrict__ bias, const float* __restrict__ extra, float scale,
    int K, int ldc,
    int rsA, int csA, int ssA, int rsB, int csB, int ssB,
    long zA, long zB, long zC) {
  __shared__ __align__(16) UST buf[17408];  // 34 KB: staging (16 KB) then C-tile
  UST* lA = buf;
  UST* lB = buf + 4096;

  const int tid = threadIdx.x;
  const int z = blockIdx.z;
  const int m0 = blockIdx.y * 128;
  const int n0 = blockIdx.x * 128;
  const UST* Ab = A + (long)z * zA;
  const UST* Bb = B + (long)z * zB;

  const int w = tid >> 6, lane = tid & 63;
  const int quad = lane >> 4, l16 = lane & 15;
  const int wm = w >> 1, wn = w & 1;  // 2x2 waves, each 64x64

  f32x4 acc[4][4];
#pragma unroll
  for (int i = 0; i < 4; i++)
#pragma unroll
    for (int j = 0; j < 4; j++) acc[i][j] = f32x4{0.f, 0.f, 0.f, 0.f};

  const int rowa = tid >> 2;   // 0..63
  const int kchunk = tid & 3;  // 8-elem chunk within 32-k step
  const UST* gA = Ab + (size_t)(m0 + rowa) * rsA + (size_t)kchunk * csA;
  const UST* gB = Bb + (size_t)(n0 + rowa) * rsB + (size_t)kchunk * csB;
  char* lAw = (char*)lA + (w << 10);
  char* lBw = (char*)lB + (w << 10);

  for (int k0 = 0; k0 < K; k0 += 32) {
    __syncthreads();
    load16(gA, lAw);
    load16(gA + (size_t)64 * rsA, lAw + 4096);
    load16(gB, lBw);
    load16(gB + (size_t)64 * rsB, lBw + 4096);
    gA += ssA; gB += ssB;
    __syncthreads();
    bf16x8 af[4], bfr[4];
#pragma unroll
    for (int i = 0; i < 4; i++)
      af[i] = *(const bf16x8*)(lA + (wm * 64 + i * 16 + l16) * 32 + quad * 8);
#pragma unroll
    for (int j = 0; j < 4; j++)
      bfr[j] = *(const bf16x8*)(lB + (wn * 64 + j * 16 + l16) * 32 + quad * 8);
#pragma unroll
    for (int i = 0; i < 4; i++)
#pragma unroll
      for (int j = 0; j < 4; j++)
        acc[i][j] = __builtin_amdgcn_mfma_f32_16x16x32_bf16(af[i], bfr[j], acc[i][j], 0, 0, 0);
  }

  __syncthreads();  // all waves done with lA/lB before reuse as C-tile

  // C/D layout (verified m89/m91): col = lane&15, row = quad*4 + reg
  if constexpr (EPI == 4) {
    // fp32 out + bias[row] + residual, staged in two 64-row halves (stride 132)
    float* fbuf = (float*)buf;
    float* Cb = (float*)C + (long)z * zC;
    const float* Eb = extra + (long)z * zC;
#pragma unroll
    for (int h = 0; h < 2; h++) {
      if (wm == h) {
#pragma unroll
        for (int i = 0; i < 4; i++)
#pragma unroll
          for (int j = 0; j < 4; j++)
#pragma unroll
            for (int r = 0; r < 4; r++)
              fbuf[(i * 16 + quad * 4 + r) * 132 + wn * 64 + j * 16 + l16] = acc[i][j][r];
      }
      __syncthreads();
#pragma unroll
      for (int it = 0; it < 8; it++) {
        int q = tid + it * 256;          // 0..2047
        int row = q >> 5, colc = q & 31; // 64 rows x 32 float4-chunks
        int gr = m0 + h * 64 + row;
        size_t off = (size_t)gr * ldc + n0 + colc * 4;
        float4 v = *(float4*)&fbuf[row * 132 + colc * 4];
        float4 e = *(const float4*)&Eb[off];
        float bb = bias[gr];
        v.x += bb + e.x; v.y += bb + e.y; v.z += bb + e.z; v.w += bb + e.w;
        *(float4*)&Cb[off] = v;
      }
      __syncthreads();
    }
  } else {
    const bool vreg = (EPI == 6) && (n0 >= 1024);
#pragma unroll
    for (int i = 0; i < 4; i++)
#pragma unroll
      for (int j = 0; j < 4; j++) {
        float bc = 0.f;
        if constexpr (EPI == 6) bc = bias[n0 + wn * 64 + j * 16 + l16];
#pragma unroll
        for (int r = 0; r < 4; r++) {
          float v = acc[i][j][r] + bc;
          if constexpr (EPI == 5) v *= scale;
          const int lr = wm * 64 + i * 16 + quad * 4 + r;
          const int lc = wn * 64 + j * 16 + l16;
          if (!vreg) buf[lr * 136 + lc] = f2bf(v);   // row-major tile
          else       buf[lc * 136 + lr] = f2bf(v);   // transposed (V region)
        }
      }
    __syncthreads();
    if (!vreg) {
      UST* Cb = (UST*)C + (long)z * zC;
#pragma unroll
      for (int it = 0; it < 8; it++) {
        int q = tid + it * 256;
        int row = q >> 4, colc = q & 15;
        us8 v = *(us8*)&buf[row * 136 + colc * 8];
        *(us8*)&Cb[(size_t)(m0 + row) * ldc + n0 + colc * 8] = v;
      }
    } else {
      UST* Vb = (UST*)extra + (long)z * 524288;  // V (c,m) per batch
#pragma unroll
      for (int it = 0; it < 8; it++) {
        int q = tid + it * 256;
        int c = q >> 4, mc = q & 15;
        us8 v = *(us8*)&buf[c * 136 + mc * 8];
        *(us8*)&Vb[(size_t)(n0 - 1024 + c) * 1024 + m0 + mc * 8] = v;
      }
    }
  }
}

extern "C" void kernel_launch(void* const* d_in, const int* in_sizes, int n_in,
                              void* d_out, int out_size, void* d_ws, size_t ws_size,
                              hipStream_t stream) {
  const float* inp   = (const float*)d_in[0];
  const float* gamma = (const float*)d_in[1];
  const float* beta  = (const float*)d_in[2];
  const float* Wq    = (const float*)d_in[3];
  const float* bq    = (const float*)d_in[4];
  const float* Wk    = (const float*)d_in[5];
  const float* bk    = (const float*)d_in[6];
  const float* Wv    = (const float*)d_in[7];
  const float* bv    = (const float*)d_in[8];
  const float* Wo    = (const float*)d_in[9];
  const float* bo    = (const float*)d_in[10];
  float* out = (float*)d_out;
  char* ws = (char*)d_ws;

  // workspace layout (bytes)
  UST*   Xnt   = (UST*)(ws);                           // 16 MB interleaved; reused as At
  UST*   QKt   = (UST*)(ws + ((size_t)16 << 20));      // 32 MB (b,n,1024); reused as P
  UST*   V     = (UST*)(ws + ((size_t)48 << 20));      // 16 MB (b,c,m)
  UST*   S     = (UST*)(ws + ((size_t)64 << 20));      // 32 MB (b,n,m)
  float* bqkv  = (float*)(ws + ((size_t)96 << 20));    // 6 KB
  UST*   Wqkvb = (UST*)(ws + ((size_t)96 << 20) + 8192);  // 1.5 MB (1536x512)
  UST*   Wob   = Wqkvb + 786432;                       // 512 KB
  UST*   P     = QKt;
  UST*   At    = Xnt;

  conv_w<<<256, 256, 0, stream>>>(
      (const float4*)Wq, (const float4*)Wk, (const float4*)Wv, (const float4*)Wo,
      (ushort4*)Wqkvb, (ushort4*)Wob,
      (const float4*)bq, (const float4*)bk, (const float4*)bv, (float4*)bqkv);
  gn_fused<<<512, 256, 0, stream>>>(inp, gamma, beta, Xnt);

  // QKV: rows n (per batch), cols 0..1023 -> QKt ; cols 1024..1535 -> V (transposed)
  gemm_bt<6><<<dim3(12, 8, 16), 256, 0, stream>>>(
      Xnt, Wqkvb, QKt, bqkv, (const float*)V, 1.f,
      512, 1024, 8, 8192, 32768, 512, 8, 32, 524288, 0, 1048576);
  // S(b: 1024x1024) bf16 = (Q_b @ K_b^T) / sqrt(512)
  gemm_bt<5><<<dim3(8, 8, 16), 256, 0, stream>>>(
      QKt, QKt + 512, S, nullptr, nullptr, 0.04419417382415922f,
      512, 1024, 1024, 8, 32, 1024, 8, 32, 1048576, 1048576, 1048576);
  softmax_k<<<4096, 256, 0, stream>>>(S, P);
  // At(b: 1024x512) = P_b @ V_b^T
  gemm_bt<3><<<dim3(4, 8, 16), 256, 0, stream>>>(
      P, V, At, nullptr, nullptr, 1.f,
      1024, 512, 1024, 8, 32, 1024, 8, 32, 1048576, 524288, 524288);
  // out(b: 512x1024) = Wo @ At_b^T + bo[row] + inp (residual)
  gemm_bt<4><<<dim3(8, 4, 16), 256, 0, stream>>>(
      Wob, At, out, bo, inp, 1.f,
      512, 1024, 512, 8, 32, 512, 8, 32, 0, 524288, 524288);
}

// Round 4
// 238.527 us; speedup vs baseline: 1.1001x; 1.0268x over previous
//
#include <hip/hip_runtime.h>

typedef unsigned short UST;
typedef __attribute__((ext_vector_type(8))) short bf16x8;
typedef __attribute__((ext_vector_type(8))) unsigned short us8;
typedef __attribute__((ext_vector_type(4))) float f32x4;

__device__ __forceinline__ UST f2bf(float f) {
  union { float f; unsigned int u; } x; x.f = f;
  unsigned int r = x.u + 0x7fffu + ((x.u >> 16) & 1u);
  return (UST)(r >> 16);
}
__device__ __forceinline__ float bf2f(UST h) {
  union { unsigned int u; float f; } x; x.u = ((unsigned int)h) << 16;
  return x.f;
}

// CK-style barriers: sync_lds drains LDS ops only (NOT vmcnt) then barriers;
// barrier_nowait is a bare s_barrier. Both carry a memory clobber so the
// compiler cannot move LDS/global ops across them.
__device__ __forceinline__ void sync_lds() {
  asm volatile("s_waitcnt lgkmcnt(0)\n\ts_barrier" ::: "memory");
}
__device__ __forceinline__ void barrier_nowait() {
  asm volatile("s_barrier" ::: "memory");
}

// ---- fp32 -> bf16 weights: Wq,Wk,Wv packed -> Wqkv (1536x512); Wo; bqkv ----
__global__ __launch_bounds__(256) void conv_w(
    const float4* __restrict__ wq, const float4* __restrict__ wk,
    const float4* __restrict__ wv, const float4* __restrict__ wo,
    ushort4* __restrict__ oqkv, ushort4* __restrict__ owo,
    const float4* __restrict__ bq4, const float4* __restrict__ bk4,
    const float4* __restrict__ bv4, float4* __restrict__ bqkv4) {
  int i = blockIdx.x * 256 + threadIdx.x;  // 65536 float4 per matrix
  float4 v;
  v = wq[i]; oqkv[i]          = make_ushort4(f2bf(v.x), f2bf(v.y), f2bf(v.z), f2bf(v.w));
  v = wk[i]; oqkv[i + 65536]  = make_ushort4(f2bf(v.x), f2bf(v.y), f2bf(v.z), f2bf(v.w));
  v = wv[i]; oqkv[i + 131072] = make_ushort4(f2bf(v.x), f2bf(v.y), f2bf(v.z), f2bf(v.w));
  v = wo[i]; owo[i]           = make_ushort4(f2bf(v.x), f2bf(v.y), f2bf(v.z), f2bf(v.w));
  if (blockIdx.x < 2) {
    int t = blockIdx.x * 256 + threadIdx.x;
    if (t < 384) bqkv4[t] = (t < 128) ? bq4[t] : (t < 256 ? bk4[t - 128] : bv4[t - 256]);
  }
}

// ---- fused GroupNorm: stats + normalize + transposed-interleaved write -----
// Xnt layout per batch: element (n,c) at (c>>3)*8192 + n*8 + (c&7)  [bf16]
__global__ __launch_bounds__(256) void gn_fused(
    const float* __restrict__ inp, const float* __restrict__ gamma,
    const float* __restrict__ beta, UST* __restrict__ Xnt) {
  const int g = blockIdx.x & 31, b = blockIdx.x >> 5;
  const int tid = threadIdx.x;
  const float* base = inp + ((size_t)b * 32 + g) * 16384;
  const float4* p4 = (const float4*)base;
  float s = 0.f, ss = 0.f;
#pragma unroll
  for (int i = 0; i < 16; i++) {
    float4 t = p4[tid + i * 256];
    s += t.x + t.y + t.z + t.w;
    ss += t.x * t.x + t.y * t.y + t.z * t.z + t.w * t.w;
  }
  for (int o = 32; o >= 1; o >>= 1) { s += __shfl_xor(s, o); ss += __shfl_xor(ss, o); }
  __shared__ float red[8];
  __shared__ float mu_s, rstd_s;
  const int w = tid >> 6;
  if ((tid & 63) == 0) { red[w * 2] = s; red[w * 2 + 1] = ss; }
  __syncthreads();
  if (tid == 0) {
    float S1 = red[0] + red[2] + red[4] + red[6];
    float S2 = red[1] + red[3] + red[5] + red[7];
    float mu = S1 * (1.f / 16384.f);
    float var = S2 * (1.f / 16384.f) - mu * mu;
    mu_s = mu; rstd_s = rsqrtf(var + 1e-6f);
  }
  __syncthreads();
  const float mu = mu_s, rstd = rstd_s;
#pragma unroll
  for (int cc = 0; cc < 2; cc++) {
    const int ccg = g * 2 + cc;
    float sc[8], sh[8];
#pragma unroll
    for (int j = 0; j < 8; j++) {
      int ch = ccg * 8 + j;
      sc[j] = gamma[ch] * rstd;
      sh[j] = beta[ch] - mu * sc[j];
    }
#pragma unroll
    for (int i = 0; i < 4; i++) {
      const int n = tid + i * 256;
      us8 v;
#pragma unroll
      for (int j = 0; j < 8; j++) {
        float x = inp[((size_t)b * 512 + ccg * 8 + j) * 1024 + n];
        v[j] = f2bf(x * sc[j] + sh[j]);
      }
      *(us8*)(Xnt + (size_t)b * 524288 + (size_t)ccg * 8192 + (size_t)n * 8) = v;
    }
  }
}

// ---- row softmax on bf16 scores: S(16384x1024) bf16 -> P bf16 --------------
__global__ __launch_bounds__(256) void softmax_k(const UST* __restrict__ S,
                                                 UST* __restrict__ P) {
  const int w = threadIdx.x >> 6, lane = threadIdx.x & 63;
  const size_t row = (size_t)blockIdx.x * 4 + w;
  const us8* Sr = (const us8*)(S + row * 1024);
  us8 a = Sr[lane], b = Sr[64 + lane];
  float v[16];
#pragma unroll
  for (int j = 0; j < 8; j++) { v[j] = bf2f(a[j]); v[8 + j] = bf2f(b[j]); }
  float m = v[0];
#pragma unroll
  for (int i = 1; i < 16; i++) m = fmaxf(m, v[i]);
#pragma unroll
  for (int o = 32; o >= 1; o >>= 1) m = fmaxf(m, __shfl_xor(m, o));
  float s = 0.f;
#pragma unroll
  for (int i = 0; i < 16; i++) { v[i] = __expf(v[i] - m); s += v[i]; }
#pragma unroll
  for (int o = 32; o >= 1; o >>= 1) s += __shfl_xor(s, o);
  const float rs = 1.f / s;
  us8* Pr = (us8*)(P + row * 1024);
  us8 oa, ob;
#pragma unroll
  for (int j = 0; j < 8; j++) { oa[j] = f2bf(v[j] * rs); ob[j] = f2bf(v[8 + j] * rs); }
  Pr[lane] = oa; Pr[64 + lane] = ob;
}

// ---- gemm_bt: C[i][j] = sum_k A[i][k]*B[j][k] -------------------------------
// Register-prefetch pipelined K-loop (loads tile k+1 into VGPRs while MFMAs
// run on tile k; raw barriers avoid the __syncthreads vmcnt(0) drain).
// LDS staging padded to 40 UST/row (conflict-free frag reads).
// 16B chunk (row,kchunk) of operand at row*rs + kchunk*cs, advancing ss per 32-k.
// EPI 6: QKV - bf16 +bias[col]; n0<1024 -> QKt row-major; n0>=1024 -> V
//        transposed into (c,m) layout (V base via `extra`, z-stride 524288)
// EPI 5: bf16 *scale | EPI 3: bf16 | EPI 4: f32 +bias[row] +extra (residual)
template <int EPI>
__global__ __launch_bounds__(256, 2) void gemm_bt(
    const UST* __restrict__ A, const UST* __restrict__ B, void* __restrict__ C,
    const float* __restrict__ bias, const float* __restrict__ extra, float scale,
    int K, int ldc,
    int rsA, int csA, int ssA, int rsB, int csB, int ssB,
    long zA, long zB, long zC) {
  // 20480 B: staging = 2 x (128 rows x 40 UST); epilogue sub-tiles alias it.
  __shared__ __align__(16) UST buf[10240];
  UST* lA = buf;
  UST* lB = buf + 5120;

  const int tid = threadIdx.x;
  const int z = blockIdx.z;
  const int m0 = blockIdx.y * 128;
  const int n0 = blockIdx.x * 128;
  const UST* Ab = A + (long)z * zA;
  const UST* Bb = B + (long)z * zB;

  const int w = tid >> 6, lane = tid & 63;
  const int quad = lane >> 4, l16 = lane & 15;
  const int wm = w >> 1, wn = w & 1;  // 2x2 waves, each 64x64

  f32x4 acc[4][4];
#pragma unroll
  for (int i = 0; i < 4; i++)
#pragma unroll
    for (int j = 0; j < 4; j++) acc[i][j] = f32x4{0.f, 0.f, 0.f, 0.f};

  const int rowa = tid >> 2;   // 0..63
  const int kchunk = tid & 3;  // 8-elem chunk within 32-k step
  const UST* gA = Ab + (size_t)(m0 + rowa) * rsA + (size_t)kchunk * csA;
  const UST* gB = Bb + (size_t)(n0 + rowa) * rsB + (size_t)kchunk * csB;
  const size_t a64 = (size_t)64 * rsA, b64 = (size_t)64 * rsB;
  UST* wA = lA + rowa * 40 + kchunk * 8;
  UST* wB = lB + rowa * 40 + kchunk * 8;

  // preload tile 0
  us8 pa0 = *(const us8*)gA, pa1 = *(const us8*)(gA + a64);
  us8 pb0 = *(const us8*)gB, pb1 = *(const us8*)(gB + b64);

  const int nk = K >> 5;
  for (int k = 0; k < nk; ++k) {
    us8 na0, na1, nb0, nb1;
    if (k + 1 < nk) {  // issue next-tile loads first; in flight through MFMAs
      gA += ssA; gB += ssB;
      na0 = *(const us8*)gA; na1 = *(const us8*)(gA + a64);
      nb0 = *(const us8*)gB; nb1 = *(const us8*)(gB + b64);
    }
    if (k) barrier_nowait();  // prev tile's LDS reads done (consumed pre-barrier)
    *(us8*)wA = pa0; *(us8*)(wA + 2560) = pa1;
    *(us8*)wB = pb0; *(us8*)(wB + 2560) = pb1;
    sync_lds();  // lgkmcnt(0) + s_barrier; vmcnt (prefetch) stays in flight
    bf16x8 af[4], bfr[4];
#pragma unroll
    for (int i = 0; i < 4; i++)
      af[i] = *(const bf16x8*)(lA + (wm * 64 + i * 16 + l16) * 40 + quad * 8);
#pragma unroll
    for (int j = 0; j < 4; j++)
      bfr[j] = *(const bf16x8*)(lB + (wn * 64 + j * 16 + l16) * 40 + quad * 8);
#pragma unroll
    for (int i = 0; i < 4; i++)
#pragma unroll
      for (int j = 0; j < 4; j++)
        acc[i][j] = __builtin_amdgcn_mfma_f32_16x16x32_bf16(af[i], bfr[j], acc[i][j], 0, 0, 0);
    pa0 = na0; pa1 = na1; pb0 = nb0; pb1 = nb1;
  }

  barrier_nowait();  // all waves done with staging before reuse as C-tile

  // C/D layout (verified m89/m91): col = lane&15, row = quad*4 + reg
  if constexpr (EPI == 4) {
    // fp32 out + bias[row] + residual; four 32-row x 132-float phases (16.9 KB)
    float* fbuf = (float*)buf;
    float* Cb = (float*)C + (long)z * zC;
    const float* Eb = extra + (long)z * zC;
#pragma unroll
    for (int p = 0; p < 4; ++p) {
      if (p) barrier_nowait();
      if (wm == (p >> 1)) {
#pragma unroll
        for (int ii = 0; ii < 2; ii++) {
          const int i = (p & 1) * 2 + ii;
#pragma unroll
          for (int j = 0; j < 4; j++)
#pragma unroll
            for (int r = 0; r < 4; r++)
              fbuf[(ii * 16 + quad * 4 + r) * 132 + wn * 64 + j * 16 + l16] = acc[i][j][r];
        }
      }
      sync_lds();
#pragma unroll
      for (int it = 0; it < 4; ++it) {
        int q = tid + it * 256;            // 0..1023
        int row = q >> 5, colc = q & 31;   // 32 rows x 32 float4
        int gr = m0 + p * 32 + row;
        size_t off = (size_t)gr * ldc + n0 + colc * 4;
        float4 v = *(float4*)&fbuf[row * 132 + colc * 4];
        float4 e = *(const float4*)&Eb[off];
        float bb = bias[gr];
        v.x += bb + e.x; v.y += bb + e.y; v.z += bb + e.z; v.w += bb + e.w;
        *(float4*)&Cb[off] = v;
      }
    }
  } else {
    const bool vreg = (EPI == 6) && (n0 >= 1024);
    if (!vreg) {
      // bf16 row-major tile in two 64-row x 136-UST phases (17.4 KB)
      UST* Cb = (UST*)C + (long)z * zC;
#pragma unroll
      for (int h = 0; h < 2; ++h) {
        if (h) barrier_nowait();
        if (wm == h) {
#pragma unroll
          for (int i = 0; i < 4; i++)
#pragma unroll
            for (int j = 0; j < 4; j++) {
              float bc = 0.f;
              if constexpr (EPI == 6) bc = bias[n0 + wn * 64 + j * 16 + l16];
#pragma unroll
              for (int r = 0; r < 4; r++) {
                float v = acc[i][j][r] + bc;
                if constexpr (EPI == 5) v *= scale;
                buf[(i * 16 + quad * 4 + r) * 136 + wn * 64 + j * 16 + l16] = f2bf(v);
              }
            }
        }
        sync_lds();
#pragma unroll
        for (int it = 0; it < 4; ++it) {
          int q = tid + it * 256;
          int row = q >> 4, colc = q & 15;  // 64 rows x 16 us8
          us8 v = *(us8*)&buf[row * 136 + colc * 8];
          *(us8*)&Cb[(size_t)(m0 + h * 64 + row) * ldc + n0 + colc * 8] = v;
        }
      }
    } else {
      // V region: transpose into (c,m); two 64-col x 136-UST phases
      UST* Vb = (UST*)extra + (long)z * 524288;
#pragma unroll
      for (int h = 0; h < 2; ++h) {
        if (h) barrier_nowait();
        if (wn == h) {
#pragma unroll
          for (int i = 0; i < 4; i++)
#pragma unroll
            for (int j = 0; j < 4; j++) {
              const float bc = bias[n0 + wn * 64 + j * 16 + l16];
#pragma unroll
              for (int r = 0; r < 4; r++) {
                float v = acc[i][j][r] + bc;
                buf[(j * 16 + l16) * 136 + wm * 64 + i * 16 + quad * 4 + r] = f2bf(v);
              }
            }
        }
        sync_lds();
#pragma unroll
        for (int it = 0; it < 4; ++it) {
          int q = tid + it * 256;
          int c = q >> 4, mc = q & 15;  // 64 channels x 16 us8 along m
          us8 v = *(us8*)&buf[c * 136 + mc * 8];
          *(us8*)&Vb[(size_t)(n0 - 1024 + h * 64 + c) * 1024 + m0 + mc * 8] = v;
        }
      }
    }
  }
}

extern "C" void kernel_launch(void* const* d_in, const int* in_sizes, int n_in,
                              void* d_out, int out_size, void* d_ws, size_t ws_size,
                              hipStream_t stream) {
  const float* inp   = (const float*)d_in[0];
  const float* gamma = (const float*)d_in[1];
  const float* beta  = (const float*)d_in[2];
  const float* Wq    = (const float*)d_in[3];
  const float* bq    = (const float*)d_in[4];
  const float* Wk    = (const float*)d_in[5];
  const float* bk    = (const float*)d_in[6];
  const float* Wv    = (const float*)d_in[7];
  const float* bv    = (const float*)d_in[8];
  const float* Wo    = (const float*)d_in[9];
  const float* bo    = (const float*)d_in[10];
  float* out = (float*)d_out;
  char* ws = (char*)d_ws;

  UST*   Xnt   = (UST*)(ws);                           // 16 MB interleaved; reused as At
  UST*   QKt   = (UST*)(ws + ((size_t)16 << 20));      // 32 MB (b,n,1024); reused as P
  UST*   V     = (UST*)(ws + ((size_t)48 << 20));      // 16 MB (b,c,m)
  UST*   S     = (UST*)(ws + ((size_t)64 << 20));      // 32 MB (b,n,m)
  float* bqkv  = (float*)(ws + ((size_t)96 << 20));    // 6 KB
  UST*   Wqkvb = (UST*)(ws + ((size_t)96 << 20) + 8192);  // 1.5 MB (1536x512)
  UST*   Wob   = Wqkvb + 786432;                       // 512 KB
  UST*   P     = QKt;
  UST*   At    = Xnt;

  conv_w<<<256, 256, 0, stream>>>(
      (const float4*)Wq, (const float4*)Wk, (const float4*)Wv, (const float4*)Wo,
      (ushort4*)Wqkvb, (ushort4*)Wob,
      (const float4*)bq, (const float4*)bk, (const float4*)bv, (float4*)bqkv);
  gn_fused<<<512, 256, 0, stream>>>(inp, gamma, beta, Xnt);

  // QKV: rows n (per batch), cols 0..1023 -> QKt ; cols 1024..1535 -> V (transposed)
  gemm_bt<6><<<dim3(12, 8, 16), 256, 0, stream>>>(
      Xnt, Wqkvb, QKt, bqkv, (const float*)V, 1.f,
      512, 1024, 8, 8192, 32768, 512, 8, 32, 524288, 0, 1048576);
  // S(b: 1024x1024) bf16 = (Q_b @ K_b^T) / sqrt(512)
  gemm_bt<5><<<dim3(8, 8, 16), 256, 0, stream>>>(
      QKt, QKt + 512, S, nullptr, nullptr, 0.04419417382415922f,
      512, 1024, 1024, 8, 32, 1024, 8, 32, 1048576, 1048576, 1048576);
  softmax_k<<<4096, 256, 0, stream>>>(S, P);
  // At(b: 1024x512) = P_b @ V_b^T
  gemm_bt<3><<<dim3(4, 8, 16), 256, 0, stream>>>(
      P, V, At, nullptr, nullptr, 1.f,
      1024, 512, 1024, 8, 32, 1024, 8, 32, 1048576, 524288, 524288);
  // out(b: 512x1024) = Wo @ At_b^T + bo[row] + inp (residual)
  gemm_bt<4><<<dim3(8, 4, 16), 256, 0, stream>>>(
      Wob, At, out, bo, inp, 1.f,
      512, 1024, 512, 8, 32, 512, 8, 32, 0, 524288, 524288);
}